// Round 3
// baseline (9197.316 us; speedup 1.0000x reference)
//
#include <hip/hip_runtime.h>
#include <hip/hip_bf16.h>

// ---------------------------------------------------------------------------
// Model: GCN stack (ir_Learner + main gnn + decoder) + linear CKA + LayerNorm
// N=100000 nodes, E=1.6M edges, D=H=128. All fp32 (correctness baseline).
// Aggregation via float atomics; GEMM via LDS-staged fp32 tiles, run
// IN-PLACE (each block reads only its own 32 rows, all reads precede writes)
// so the workspace needs only 3 N x 128 buffers (~154 MB).
// ---------------------------------------------------------------------------

#define HD 128

// ---- degree / normalization ----------------------------------------------
__global__ void k_deg(const int* __restrict__ dst, float* __restrict__ deg, int E) {
  int i = blockIdx.x * blockDim.x + threadIdx.x;
  if (i < E) atomicAdd(&deg[dst[i]], 1.0f);
}

__global__ void k_dis(float* __restrict__ deg, int n) {
  int i = blockIdx.x * blockDim.x + threadIdx.x;
  if (i < n) deg[i] = rsqrtf(deg[i] + 1.0f);  // +1 self-loop; always >= 1
}

// ---- GEMM: C[n x 128] = X[n x K] @ W[K x 128] -----------------------------
// X2 supplies columns 128..255 when K==256 (concat case). Row stride of X1/X2
// is 128 floats. Tile: 32 rows x 128 cols per block, 256 threads,
// each thread 4 rows x 4 cols. K staged in 64-chunks (W: 32KB, X: 8KB LDS).
// In-place safe: block touches only rows [row0,row0+32) of X and C, and all
// global X reads happen before any C write.
template<int K>
__global__ __launch_bounds__(256) void k_gemm(const float* __restrict__ X1,
    const float* __restrict__ X2, const float* __restrict__ W,
    float* __restrict__ C, int n) {
  __shared__ float Ws[64 * 128];
  __shared__ float Xs[32 * 64];
  const int tid = threadIdx.x;
  const int row0 = blockIdx.x * 32;
  const int rg = tid >> 5;         // 0..7
  const int c0 = (tid & 31) * 4;   // 0,4,...,124
  float acc[4][4] = {};
  for (int kc = 0; kc < K; kc += 64) {
    const float* Xp = (kc < 128) ? X1 : X2;
    const int kof = (kc < 128) ? kc : kc - 128;
    __syncthreads();
    // stage W chunk [64][128] (contiguous)
    {
      const float4* Wg = (const float4*)(W + (size_t)kc * 128);
      float4* Wl = (float4*)Ws;
      for (int v = tid; v < 64 * 128 / 4; v += 256) Wl[v] = Wg[v];
    }
    // stage X chunk [32][64]
    for (int v = tid; v < 32 * 64 / 4; v += 256) {
      int r = v >> 4, k4 = v & 15;
      int rr = row0 + r; if (rr > n - 1) rr = n - 1;
      ((float4*)(Xs + r * 64))[k4] =
          ((const float4*)(Xp + (size_t)rr * 128 + kof))[k4];
    }
    __syncthreads();
#pragma unroll
    for (int k4 = 0; k4 < 64; k4 += 4) {
      float4 xv[4];
#pragma unroll
      for (int i = 0; i < 4; ++i)
        xv[i] = *(const float4*)(Xs + (rg + 8 * i) * 64 + k4);
#pragma unroll
      for (int kk = 0; kk < 4; ++kk) {
        float4 w = *(const float4*)(Ws + (k4 + kk) * 128 + c0);
#pragma unroll
        for (int i = 0; i < 4; ++i) {
          float x = ((const float*)&xv[i])[kk];
          acc[i][0] = fmaf(x, w.x, acc[i][0]);
          acc[i][1] = fmaf(x, w.y, acc[i][1]);
          acc[i][2] = fmaf(x, w.z, acc[i][2]);
          acc[i][3] = fmaf(x, w.w, acc[i][3]);
        }
      }
    }
  }
#pragma unroll
  for (int i = 0; i < 4; ++i) {
    int r = row0 + rg + 8 * i;
    if (r < n) {
      float4 o = { acc[i][0], acc[i][1], acc[i][2], acc[i][3] };
      *(float4*)(C + (size_t)r * 128 + c0) = o;
    }
  }
}

// ---- edge scatter: agg[dst] += h[src] * dis[src]*dis[dst] -----------------
// one wave per edge, 2 floats per lane
__global__ __launch_bounds__(256) void k_scatter(const float* __restrict__ h,
    float* __restrict__ agg, const int* __restrict__ src,
    const int* __restrict__ dst, const float* __restrict__ dis, int E) {
  int e = (blockIdx.x * 256 + threadIdx.x) >> 6;
  if (e >= E) return;
  int lane = threadIdx.x & 63;
  int s = src[e], d = dst[e];
  float c = dis[s] * dis[d];
  float2 hv = *(const float2*)(h + (size_t)s * HD + lane * 2);
  float* ap = agg + (size_t)d * HD + lane * 2;
  atomicAdd(ap, hv.x * c);
  atomicAdd(ap + 1, hv.y * c);
}

// ---- finish: out = act(agg + h*dis^2 + b) ---------------------------------
// act: 0 none, 1 relu, 2 tanh. One float4 per thread.
__global__ void k_finish(const float* __restrict__ agg, const float* __restrict__ h,
    const float* __restrict__ dis, const float* __restrict__ b,
    float* __restrict__ out, int act, int total4) {
  int i = blockIdx.x * blockDim.x + threadIdx.x;
  if (i >= total4) return;
  int row = i >> 5;       // 32 float4 per row
  int c4 = i & 31;
  float sc = dis[row]; sc *= sc;
  float4 a = ((const float4*)agg)[i];
  float4 hv = ((const float4*)h)[i];
  float4 bv = ((const float4*)b)[c4];
  float4 v;
  v.x = fmaf(hv.x, sc, a.x) + bv.x;
  v.y = fmaf(hv.y, sc, a.y) + bv.y;
  v.z = fmaf(hv.z, sc, a.z) + bv.z;
  v.w = fmaf(hv.w, sc, a.w) + bv.w;
  if (act == 1) {
    v.x = fmaxf(v.x, 0.f); v.y = fmaxf(v.y, 0.f);
    v.z = fmaxf(v.z, 0.f); v.w = fmaxf(v.w, 0.f);
  } else if (act == 2) {
    v.x = tanhf(v.x); v.y = tanhf(v.y); v.z = tanhf(v.z); v.w = tanhf(v.w);
  }
  ((float4*)out)[i] = v;
}

// ---- column sums of env (A) and inv (B): sums[0:128]=A, sums[128:256]=B ---
__global__ void k_colsum(const float* __restrict__ A, const float* __restrict__ B,
                         float* __restrict__ sums, int N) {
  int col = threadIdx.x & 127;
  int sel = threadIdx.x >> 7;
  const float* P = sel ? B : A;
  float s = 0.f;
  for (int r = blockIdx.x; r < N; r += gridDim.x)
    s += P[(size_t)r * HD + col];
  atomicAdd(&sums[sel * HD + col], s);
}

// ---- Gram matrices: G[g][128][128], g: 0=env'env 1=inv'inv 2=env'inv ------
__global__ __launch_bounds__(256) void k_gram(const float* __restrict__ env,
    const float* __restrict__ inv, const float* __restrict__ sums,
    float* __restrict__ G, int N) {
  const int g = blockIdx.y;
  const float* X = (g == 1) ? inv : env;
  const float* Y = (g == 0) ? env : inv;
  const float* mxs = sums + ((g == 1) ? HD : 0);
  const float* mys = sums + ((g == 0) ? 0 : HD);
  __shared__ float Xs[8 * HD], Ys[8 * HD];
  __shared__ float mux[HD], muy[HD];
  const int tid = threadIdx.x;
  if (tid < HD) mux[tid] = mxs[tid] * (1.0f / N);
  else muy[tid - HD] = mys[tid - HD] * (1.0f / N);
  const int i0 = (tid >> 4) * 8;   // 16 groups
  const int j0 = (tid & 15) * 8;
  float acc[8][8] = {};
  __syncthreads();
  for (int r0 = blockIdx.x * 8; r0 < N; r0 += gridDim.x * 8) {
    __syncthreads();
    for (int t = tid; t < 8 * HD; t += 256) {
      int rr = t >> 7, cc = t & 127;
      int r = r0 + rr;
      float xv = 0.f, yv = 0.f;
      if (r < N) {
        xv = X[(size_t)r * HD + cc] - mux[cc];
        yv = Y[(size_t)r * HD + cc] - muy[cc];
      }
      Xs[rr * HD + cc] = xv;
      Ys[rr * HD + cc] = yv;
    }
    __syncthreads();
#pragma unroll
    for (int rr = 0; rr < 8; ++rr) {
      float4 xa = *(const float4*)(Xs + rr * HD + i0);
      float4 xb = *(const float4*)(Xs + rr * HD + i0 + 4);
      float4 ya = *(const float4*)(Ys + rr * HD + j0);
      float4 yb = *(const float4*)(Ys + rr * HD + j0 + 4);
      float xv[8] = {xa.x, xa.y, xa.z, xa.w, xb.x, xb.y, xb.z, xb.w};
      float yv[8] = {ya.x, ya.y, ya.z, ya.w, yb.x, yb.y, yb.z, yb.w};
#pragma unroll
      for (int i = 0; i < 8; ++i)
#pragma unroll
        for (int j = 0; j < 8; ++j)
          acc[i][j] = fmaf(xv[i], yv[j], acc[i][j]);
    }
  }
  float* Gp = G + (size_t)g * HD * HD;
#pragma unroll
  for (int i = 0; i < 8; ++i)
#pragma unroll
    for (int j = 0; j < 8; ++j)
      atomicAdd(&Gp[(size_t)(i0 + i) * HD + (j0 + j)], acc[i][j]);
}

// ---- final CKA scalar -----------------------------------------------------
__global__ void k_cka(const float* __restrict__ G, float* __restrict__ out0) {
  float sxx = 0.f, syy = 0.f, sxy = 0.f;
  for (int i = threadIdx.x; i < HD * HD; i += 256) {
    float a = G[i];              sxx = fmaf(a, a, sxx);
    float b = G[HD * HD + i];    syy = fmaf(b, b, syy);
    float c = G[2 * HD * HD + i]; sxy = fmaf(c, c, sxy);
  }
  for (int o = 32; o; o >>= 1) {
    sxx += __shfl_down(sxx, o);
    syy += __shfl_down(syy, o);
    sxy += __shfl_down(sxy, o);
  }
  __shared__ float red[3][4];
  int wave = threadIdx.x >> 6, lane = threadIdx.x & 63;
  if (lane == 0) { red[0][wave] = sxx; red[1][wave] = syy; red[2][wave] = sxy; }
  __syncthreads();
  if (threadIdx.x == 0) {
    float xx = red[0][0] + red[0][1] + red[0][2] + red[0][3];
    float yy = red[1][0] + red[1][1] + red[1][2] + red[1][3];
    float xy = red[2][0] + red[2][1] + red[2][2] + red[2][3];
    out0[0] = xy / (sqrtf(xx) * sqrtf(yy));
  }
}

// ---- LayerNorm over last dim (128), write to out+1 ------------------------
__global__ void k_ln(const float* __restrict__ dec, const float* __restrict__ g,
    const float* __restrict__ b, float* __restrict__ out, int N) {
  int row = blockIdx.x * 4 + (threadIdx.x >> 6);
  if (row >= N) return;
  int lane = threadIdx.x & 63;
  float2 v = *(const float2*)(dec + (size_t)row * HD + lane * 2);
  float s = v.x + v.y;
  for (int o = 32; o; o >>= 1) s += __shfl_xor(s, o);
  float mu = s * (1.0f / HD);
  float dx = v.x - mu, dy = v.y - mu;
  float q = fmaf(dx, dx, dy * dy);
  for (int o = 32; o; o >>= 1) q += __shfl_xor(q, o);
  float rs = rsqrtf(q * (1.0f / HD) + 1e-5f);
  float2 gv = *(const float2*)(g + lane * 2);
  float2 bv = *(const float2*)(b + lane * 2);
  size_t o0 = 1 + (size_t)row * HD + (size_t)lane * 2;
  out[o0]     = fmaf(dx * rs, gv.x, bv.x);
  out[o0 + 1] = fmaf(dy * rs, gv.y, bv.y);
}

// ---------------------------------------------------------------------------
extern "C" void kernel_launch(void* const* d_in, const int* in_sizes, int n_in,
                              void* d_out, int out_size, void* d_ws, size_t ws_size,
                              hipStream_t stream) {
  const float* x     = (const float*)d_in[0];
  const int*   ei    = (const int*)d_in[1];
  const float* W_ir1 = (const float*)d_in[2];
  const float* b_ir1 = (const float*)d_in[3];
  const float* W_ir2 = (const float*)d_in[4];
  const float* b_ir2 = (const float*)d_in[5];
  const float* W_g1  = (const float*)d_in[6];
  const float* b_g1  = (const float*)d_in[7];
  const float* W_g2  = (const float*)d_in[8];
  const float* b_g2  = (const float*)d_in[9];
  const float* W_d1  = (const float*)d_in[10];
  const float* b_d1  = (const float*)d_in[11];
  const float* W_d2  = (const float*)d_in[12];
  const float* b_d2  = (const float*)d_in[13];
  const float* ln_g  = (const float*)d_in[14];
  const float* ln_b  = (const float*)d_in[15];

  const int N = in_sizes[0] / HD;
  const int E = in_sizes[1] / 2;
  const int* src = ei;
  const int* dst = ei + E;
  float* out = (float*)d_out;

  const size_t NH = (size_t)N * HD;
  char* w = (char*)d_ws;
  float* A   = (float*)w; w += NH * sizeof(float);  // h1_ir / env / h_d1
  float* B   = (float*)w; w += NH * sizeof(float);  // h1_g / inv / dec
  float* Dg  = (float*)w; w += NH * sizeof(float);  // agg scratch
  float* dis = (float*)w; w += (size_t)N * sizeof(float);
  float* sums = (float*)w; w += 256 * sizeof(float);
  float* G   = (float*)w;                            // 3 * 128 * 128

  // degrees -> dis
  hipMemsetAsync(dis, 0, (size_t)N * sizeof(float), stream);
  k_deg<<<(E + 255) / 256, 256, 0, stream>>>(dst, dis, E);
  k_dis<<<(N + 255) / 256, 256, 0, stream>>>(dis, N);

  const int gblocks = (N + 31) / 32;
  const int total4 = (int)(NH / 4);
  const int fblocks = (total4 + 255) / 256;
  const int sblocks = (int)(((size_t)E * 64 + 255) / 256);

  // conv: res = act(scatter(res @ W) + selfloop + bias). GEMM runs in-place
  // into `res` (safe: per-block row ownership), scatter/finish then use it.
  auto conv = [&](const float* X1, const float* X2, int K, const float* Wm,
                  const float* bias, float* res, int act) {
    if (K == 128) k_gemm<128><<<gblocks, 256, 0, stream>>>(X1, X2, Wm, res, N);
    else          k_gemm<256><<<gblocks, 256, 0, stream>>>(X1, X2, Wm, res, N);
    hipMemsetAsync(Dg, 0, NH * sizeof(float), stream);
    k_scatter<<<sblocks, 256, 0, stream>>>(res, Dg, src, dst, dis, E);
    k_finish<<<fblocks, 256, 0, stream>>>(Dg, res, dis, bias, res, act, total4);
  };

  // env = tanh(gcn2(x, ir))
  conv(x, nullptr, 128, W_ir1, b_ir1, A, 1);   // A = relu(conv1)
  conv(A, nullptr, 128, W_ir2, b_ir2, A, 2);   // A = env = tanh(conv2)
  // inv = gcn2(x, g)
  conv(x, nullptr, 128, W_g1, b_g1, B, 1);     // B = relu(conv1)
  conv(B, nullptr, 128, W_g2, b_g2, B, 0);     // B = inv

  // CKA(env, inv) -> out[0]
  hipMemsetAsync(sums, 0, 256 * sizeof(float), stream);
  hipMemsetAsync(G, 0, 3 * HD * HD * sizeof(float), stream);
  k_colsum<<<512, 256, 0, stream>>>(A, B, sums, N);
  dim3 gg(256, 3);
  k_gram<<<gg, 256, 0, stream>>>(A, B, sums, G, N);
  k_cka<<<1, 256, 0, stream>>>(G, out);

  // decoder: gcn2(concat[env, inv], d) then LayerNorm -> out+1
  conv(A, B, 256, W_d1, b_d1, A, 1);           // A = relu(conv1(cat))
  conv(A, nullptr, 128, W_d2, b_d2, B, 0);     // B = dec
  k_ln<<<(N + 3) / 4, 256, 0, stream>>>(B, ln_g, ln_b, out, N);
}

// Round 4
// 2255.378 us; speedup vs baseline: 4.0779x; 4.0779x over previous
//
#include <hip/hip_runtime.h>
#include <hip/hip_bf16.h>

// ---------------------------------------------------------------------------
// GCN stack + linear CKA + LayerNorm.  N=100k, E=1.6M, D=H=128. fp32.
// Round 3: atomic scatter (6x1300us) replaced by CSR gather (dst-sorted,
// built once per call), with self-loop+bias+act fused into the gather and
// LayerNorm fused into the final gather. No atomics in hot path.
// ---------------------------------------------------------------------------

#define HD 128

// ---- degree count (int) ---------------------------------------------------
__global__ void k_deg(const int* __restrict__ dst, int* __restrict__ degi, int E) {
  int i = blockIdx.x * blockDim.x + threadIdx.x;
  if (i < E) atomicAdd(&degi[dst[i]], 1);
}

// ---- dis = rsqrt(deg+1) ---------------------------------------------------
__global__ void k_dis(const int* __restrict__ degi, float* __restrict__ dis, int n) {
  int i = blockIdx.x * blockDim.x + threadIdx.x;
  if (i < n) dis[i] = rsqrtf((float)degi[i] + 1.0f);
}

// ---- exclusive scan of degi -> row_ptr (N+1) and cursor copy --------------
// single block, 1024 threads, each owns a contiguous chunk.
__global__ __launch_bounds__(1024) void k_scan(const int* __restrict__ degi,
    int* __restrict__ row_ptr, int* __restrict__ cursor, int N) {
  __shared__ int s[1024];
  const int tid = threadIdx.x;
  const int chunk = (N + 1023) / 1024;
  const int beg = tid * chunk;
  const int end = min(beg + chunk, N);
  int sum = 0;
  for (int i = beg; i < end; ++i) sum += degi[i];
  s[tid] = sum;
  __syncthreads();
  for (int off = 1; off < 1024; off <<= 1) {
    int v = (tid >= off) ? s[tid - off] : 0;
    __syncthreads();
    s[tid] += v;
    __syncthreads();
  }
  int run = s[tid] - sum;  // exclusive prefix of this chunk
  for (int i = beg; i < end; ++i) {
    row_ptr[i] = run;
    cursor[i] = run;
    run += degi[i];
  }
  if (tid == 1023) row_ptr[N] = s[1023];
}

// ---- fill CSR (dst-sorted): csr_src[pos], csr_coef[pos] -------------------
__global__ void k_fill(const int* __restrict__ src, const int* __restrict__ dst,
    const float* __restrict__ dis, int* __restrict__ cursor,
    int* __restrict__ csr_src, float* __restrict__ csr_coef, int E) {
  int e = blockIdx.x * blockDim.x + threadIdx.x;
  if (e >= E) return;
  int s = src[e], d = dst[e];
  int pos = atomicAdd(&cursor[d], 1);
  csr_src[pos] = s;
  csr_coef[pos] = dis[s] * dis[d];
}

// ---- GEMM: C[n x 128] = X[n x K] @ W[K x 128] -----------------------------
// X2 supplies cols 128..255 when K==256 (concat). 32 rows x 128 cols / block.
template<int K>
__global__ __launch_bounds__(256) void k_gemm(const float* __restrict__ X1,
    const float* __restrict__ X2, const float* __restrict__ W,
    float* __restrict__ C, int n) {
  __shared__ float Ws[64 * 128];
  __shared__ float Xs[32 * 64];
  const int tid = threadIdx.x;
  const int row0 = blockIdx.x * 32;
  const int rg = tid >> 5;         // 0..7
  const int c0 = (tid & 31) * 4;   // 0,4,...,124
  float acc[4][4] = {};
  for (int kc = 0; kc < K; kc += 64) {
    const float* Xp = (kc < 128) ? X1 : X2;
    const int kof = (kc < 128) ? kc : kc - 128;
    __syncthreads();
    {
      const float4* Wg = (const float4*)(W + (size_t)kc * 128);
      float4* Wl = (float4*)Ws;
      for (int v = tid; v < 64 * 128 / 4; v += 256) Wl[v] = Wg[v];
    }
    for (int v = tid; v < 32 * 64 / 4; v += 256) {
      int r = v >> 4, k4 = v & 15;
      int rr = row0 + r; if (rr > n - 1) rr = n - 1;
      ((float4*)(Xs + r * 64))[k4] =
          ((const float4*)(Xp + (size_t)rr * 128 + kof))[k4];
    }
    __syncthreads();
#pragma unroll
    for (int k4 = 0; k4 < 64; k4 += 4) {
      float4 xv[4];
#pragma unroll
      for (int i = 0; i < 4; ++i)
        xv[i] = *(const float4*)(Xs + (rg + 8 * i) * 64 + k4);
#pragma unroll
      for (int kk = 0; kk < 4; ++kk) {
        float4 w = *(const float4*)(Ws + (k4 + kk) * 128 + c0);
#pragma unroll
        for (int i = 0; i < 4; ++i) {
          float x = ((const float*)&xv[i])[kk];
          acc[i][0] = fmaf(x, w.x, acc[i][0]);
          acc[i][1] = fmaf(x, w.y, acc[i][1]);
          acc[i][2] = fmaf(x, w.z, acc[i][2]);
          acc[i][3] = fmaf(x, w.w, acc[i][3]);
        }
      }
    }
  }
#pragma unroll
  for (int i = 0; i < 4; ++i) {
    int r = row0 + rg + 8 * i;
    if (r < n) {
      float4 o = { acc[i][0], acc[i][1], acc[i][2], acc[i][3] };
      *(float4*)(C + (size_t)r * 128 + c0) = o;
    }
  }
}

// ---- gather conv: out[d] = act( sum_in h[s]*coef + h[d]*dis^2 + bias ) ----
// one wave per node, 2 cols/lane. act: 0 none, 1 relu, 2 tanh,
// 3 = LayerNorm epilogue (ln_g/ln_b, write scalar to lnout).
__global__ __launch_bounds__(256) void k_gather(const float* __restrict__ h,
    const int* __restrict__ row_ptr, const int* __restrict__ csr_src,
    const float* __restrict__ csr_coef, const float* __restrict__ dis,
    const float* __restrict__ bias, float* __restrict__ out,
    const float* __restrict__ lng, const float* __restrict__ lnb,
    float* __restrict__ lnout, int act, int N) {
  int node = blockIdx.x * 4 + (threadIdx.x >> 6);
  if (node >= N) return;
  int lane = threadIdx.x & 63;
  int beg = row_ptr[node], end = row_ptr[node + 1];
  float ax = 0.f, ay = 0.f;
  int j = beg;
  for (; j + 2 <= end; j += 2) {
    int s0 = csr_src[j], s1 = csr_src[j + 1];
    float c0 = csr_coef[j], c1 = csr_coef[j + 1];
    float2 h0 = *(const float2*)(h + (size_t)s0 * HD + lane * 2);
    float2 h1 = *(const float2*)(h + (size_t)s1 * HD + lane * 2);
    ax = fmaf(h0.x, c0, ax); ay = fmaf(h0.y, c0, ay);
    ax = fmaf(h1.x, c1, ax); ay = fmaf(h1.y, c1, ay);
  }
  if (j < end) {
    int s0 = csr_src[j];
    float c0 = csr_coef[j];
    float2 h0 = *(const float2*)(h + (size_t)s0 * HD + lane * 2);
    ax = fmaf(h0.x, c0, ax); ay = fmaf(h0.y, c0, ay);
  }
  float sc = dis[node]; sc *= sc;
  float2 hd = *(const float2*)(h + (size_t)node * HD + lane * 2);
  float2 bv = *(const float2*)(bias + lane * 2);
  float vx = fmaf(hd.x, sc, ax) + bv.x;
  float vy = fmaf(hd.y, sc, ay) + bv.y;
  if (act == 1) { vx = fmaxf(vx, 0.f); vy = fmaxf(vy, 0.f); }
  else if (act == 2) { vx = tanhf(vx); vy = tanhf(vy); }
  if (act != 3) {
    float2 o = { vx, vy };
    *(float2*)(out + (size_t)node * HD + lane * 2) = o;
  } else {
    float s = vx + vy;
    for (int o = 32; o; o >>= 1) s += __shfl_xor(s, o);
    float mu = s * (1.0f / HD);
    float dx = vx - mu, dy = vy - mu;
    float q = fmaf(dx, dx, dy * dy);
    for (int o = 32; o; o >>= 1) q += __shfl_xor(q, o);
    float rs = rsqrtf(q * (1.0f / HD) + 1e-5f);
    float2 gv = *(const float2*)(lng + lane * 2);
    float2 lb = *(const float2*)(lnb + lane * 2);
    size_t o0 = (size_t)node * HD + (size_t)lane * 2;  // lnout already +1
    lnout[o0]     = fmaf(dx * rs, gv.x, lb.x);
    lnout[o0 + 1] = fmaf(dy * rs, gv.y, lb.y);
  }
}

// ---- column sums of env (A) and inv (B) -----------------------------------
__global__ void k_colsum(const float* __restrict__ A, const float* __restrict__ B,
                         float* __restrict__ sums, int N) {
  int col = threadIdx.x & 127;
  int sel = threadIdx.x >> 7;
  const float* P = sel ? B : A;
  float s = 0.f;
  for (int r = blockIdx.x; r < N; r += gridDim.x)
    s += P[(size_t)r * HD + col];
  atomicAdd(&sums[sel * HD + col], s);
}

// ---- Gram matrices: G[g][128][128], g: 0=env'env 1=inv'inv 2=env'inv ------
__global__ __launch_bounds__(256) void k_gram(const float* __restrict__ env,
    const float* __restrict__ inv, const float* __restrict__ sums,
    float* __restrict__ G, int N) {
  const int g = blockIdx.y;
  const float* X = (g == 1) ? inv : env;
  const float* Y = (g == 0) ? env : inv;
  const float* mxs = sums + ((g == 1) ? HD : 0);
  const float* mys = sums + ((g == 0) ? 0 : HD);
  __shared__ float Xs[8 * HD], Ys[8 * HD];
  __shared__ float mux[HD], muy[HD];
  const int tid = threadIdx.x;
  if (tid < HD) mux[tid] = mxs[tid] * (1.0f / N);
  else muy[tid - HD] = mys[tid - HD] * (1.0f / N);
  const int i0 = (tid >> 4) * 8;
  const int j0 = (tid & 15) * 8;
  float acc[8][8] = {};
  __syncthreads();
  for (int r0 = blockIdx.x * 8; r0 < N; r0 += gridDim.x * 8) {
    __syncthreads();
    for (int t = tid; t < 8 * HD; t += 256) {
      int rr = t >> 7, cc = t & 127;
      int r = r0 + rr;
      float xv = 0.f, yv = 0.f;
      if (r < N) {
        xv = X[(size_t)r * HD + cc] - mux[cc];
        yv = Y[(size_t)r * HD + cc] - muy[cc];
      }
      Xs[rr * HD + cc] = xv;
      Ys[rr * HD + cc] = yv;
    }
    __syncthreads();
#pragma unroll
    for (int rr = 0; rr < 8; ++rr) {
      float4 xa = *(const float4*)(Xs + rr * HD + i0);
      float4 xb = *(const float4*)(Xs + rr * HD + i0 + 4);
      float4 ya = *(const float4*)(Ys + rr * HD + j0);
      float4 yb = *(const float4*)(Ys + rr * HD + j0 + 4);
      float xv[8] = {xa.x, xa.y, xa.z, xa.w, xb.x, xb.y, xb.z, xb.w};
      float yv[8] = {ya.x, ya.y, ya.z, ya.w, yb.x, yb.y, yb.z, yb.w};
#pragma unroll
      for (int i = 0; i < 8; ++i)
#pragma unroll
        for (int j = 0; j < 8; ++j)
          acc[i][j] = fmaf(xv[i], yv[j], acc[i][j]);
    }
  }
  float* Gp = G + (size_t)g * HD * HD;
#pragma unroll
  for (int i = 0; i < 8; ++i)
#pragma unroll
    for (int j = 0; j < 8; ++j)
      atomicAdd(&Gp[(size_t)(i0 + i) * HD + (j0 + j)], acc[i][j]);
}

// ---- final CKA scalar -----------------------------------------------------
__global__ void k_cka(const float* __restrict__ G, float* __restrict__ out0) {
  float sxx = 0.f, syy = 0.f, sxy = 0.f;
  for (int i = threadIdx.x; i < HD * HD; i += 256) {
    float a = G[i];               sxx = fmaf(a, a, sxx);
    float b = G[HD * HD + i];     syy = fmaf(b, b, syy);
    float c = G[2 * HD * HD + i]; sxy = fmaf(c, c, sxy);
  }
  for (int o = 32; o; o >>= 1) {
    sxx += __shfl_down(sxx, o);
    syy += __shfl_down(syy, o);
    sxy += __shfl_down(sxy, o);
  }
  __shared__ float red[3][4];
  int wave = threadIdx.x >> 6, lane = threadIdx.x & 63;
  if (lane == 0) { red[0][wave] = sxx; red[1][wave] = syy; red[2][wave] = sxy; }
  __syncthreads();
  if (threadIdx.x == 0) {
    float xx = red[0][0] + red[0][1] + red[0][2] + red[0][3];
    float yy = red[1][0] + red[1][1] + red[1][2] + red[1][3];
    float xy = red[2][0] + red[2][1] + red[2][2] + red[2][3];
    out0[0] = xy / (sqrtf(xx) * sqrtf(yy));
  }
}

// ---------------------------------------------------------------------------
extern "C" void kernel_launch(void* const* d_in, const int* in_sizes, int n_in,
                              void* d_out, int out_size, void* d_ws, size_t ws_size,
                              hipStream_t stream) {
  const float* x     = (const float*)d_in[0];
  const int*   ei    = (const int*)d_in[1];
  const float* W_ir1 = (const float*)d_in[2];
  const float* b_ir1 = (const float*)d_in[3];
  const float* W_ir2 = (const float*)d_in[4];
  const float* b_ir2 = (const float*)d_in[5];
  const float* W_g1  = (const float*)d_in[6];
  const float* b_g1  = (const float*)d_in[7];
  const float* W_g2  = (const float*)d_in[8];
  const float* b_g2  = (const float*)d_in[9];
  const float* W_d1  = (const float*)d_in[10];
  const float* b_d1  = (const float*)d_in[11];
  const float* W_d2  = (const float*)d_in[12];
  const float* b_d2  = (const float*)d_in[13];
  const float* ln_g  = (const float*)d_in[14];
  const float* ln_b  = (const float*)d_in[15];

  const int N = in_sizes[0] / HD;
  const int E = in_sizes[1] / 2;
  const int* src = ei;
  const int* dst = ei + E;
  float* out = (float*)d_out;

  const size_t NH = (size_t)N * HD;
  char* w = (char*)d_ws;
  float* A       = (float*)w; w += NH * sizeof(float);      // env / h_d1
  float* B       = (float*)w; w += NH * sizeof(float);      // inv
  float* H       = (float*)w; w += NH * sizeof(float);      // gemm out
  float* dis     = (float*)w; w += (size_t)N * sizeof(float);
  int*   degi    = (int*)w;   w += (size_t)N * sizeof(int);
  int*   row_ptr = (int*)w;   w += ((size_t)N + 4) * sizeof(int);
  int*   cursor  = (int*)w;   w += (size_t)N * sizeof(int);
  int*   csr_src = (int*)w;   w += (size_t)E * sizeof(int);
  float* csr_cf  = (float*)w; w += (size_t)E * sizeof(float);
  float* sums    = (float*)w; w += 256 * sizeof(float);
  float* G       = (float*)w;                                // 3*128*128

  // ---- CSR build (once per call) ----
  hipMemsetAsync(degi, 0, (size_t)N * sizeof(int), stream);
  k_deg<<<(E + 255) / 256, 256, 0, stream>>>(dst, degi, E);
  k_dis<<<(N + 255) / 256, 256, 0, stream>>>(degi, dis, N);
  k_scan<<<1, 1024, 0, stream>>>(degi, row_ptr, cursor, N);
  k_fill<<<(E + 255) / 256, 256, 0, stream>>>(src, dst, dis, cursor,
                                              csr_src, csr_cf, E);

  const int gblocks = (N + 31) / 32;
  const int ablocks = (N + 3) / 4;

  auto conv = [&](const float* X1, const float* X2, int K, const float* Wm,
                  const float* bias, float* res, int act) {
    if (K == 128) k_gemm<128><<<gblocks, 256, 0, stream>>>(X1, X2, Wm, H, N);
    else          k_gemm<256><<<gblocks, 256, 0, stream>>>(X1, X2, Wm, H, N);
    k_gather<<<ablocks, 256, 0, stream>>>(H, row_ptr, csr_src, csr_cf, dis,
                                          bias, res, ln_g, ln_b, out + 1, act, N);
  };

  // env = tanh(gcn2(x, ir))
  conv(x, nullptr, 128, W_ir1, b_ir1, A, 1);
  conv(A, nullptr, 128, W_ir2, b_ir2, A, 2);
  // inv = gcn2(x, g)
  conv(x, nullptr, 128, W_g1, b_g1, B, 1);
  conv(B, nullptr, 128, W_g2, b_g2, B, 0);

  // CKA(env, inv) -> out[0]
  hipMemsetAsync(sums, 0, 256 * sizeof(float), stream);
  hipMemsetAsync(G, 0, 3 * HD * HD * sizeof(float), stream);
  k_colsum<<<512, 256, 0, stream>>>(A, B, sums, N);
  dim3 gg(256, 3);
  k_gram<<<gg, 256, 0, stream>>>(A, B, sums, G, N);
  k_cka<<<1, 256, 0, stream>>>(G, out);

  // decoder: gcn2(concat[env, inv]) with LayerNorm fused into final gather
  conv(A, B, 256, W_d1, b_d1, A, 1);
  conv(A, nullptr, 128, W_d2, b_d2, nullptr, 3);  // writes LN to out+1
}